// Round 3
// baseline (39509.882 us; speedup 1.0000x reference)
//
#include <hip/hip_runtime.h>

#define T_STEPS 2048
#define NBATCH  32
#define IN_DIM  64
#define RES     1024
#define LEAKF   0.3f
#define NCG     64   // column groups (16 cols each)
#define NBG     4    // batch groups (8 batches each)

typedef unsigned long long u64cp;

// ---------------------------------------------------------------------------
// Persistent kernel, round 3: tagged-word dataflow (no flags, no drains).
// State element (batch b, column k) at step t is published as ONE 64-bit
// atomic word {lo: f32 value, hi: u32 tag = t} into tg[bg][t&1][k][b].
// Consumers spin on the words themselves with relaxed agent-scope loads and
// accept each word when its tag matches t-1. The store IS the publish:
// critical path per step = one one-way MALL trip + a poll period, instead of
// store-drain + flag-store + flag-discovery + state-load (4 round trips).
// WAR on the double buffer is safe: any block writing step t has consumed
// all of step t-1, which implies every block finished reading step t-2.
// Tags from a previous replay are invalidated by a 0xFF memset per launch.
// Numerics (FMA order, reduce order) identical to the verified kernel.
// ---------------------------------------------------------------------------
__global__ __launch_bounds__(256, 1) void esn_persist(
    const float* __restrict__ inp,   // [32][2048][64]
    const float* __restrict__ Win,   // [64][1024]
    const float* __restrict__ Wres,  // [1024][1024]
    float* __restrict__ out,         // [32][2048][1024]
    u64cp* __restrict__ tg)          // ws: [4][2][1024][8] tagged state
{
    const int tid   = threadIdx.x;
    const int c_loc = tid & 15;
    const int ks    = tid >> 4;            // 0..15 : k-chunk [64*ks, 64*ks+64)
    const int cg    = blockIdx.x;          // 0..63
    const int bg    = blockIdx.y;          // 0..3
    const int c0    = cg * 16;
    const int b0    = bg * 8;
    const int c     = c0 + c_loc;

    // Hoist this thread's Wres slice into registers: w[j] = Wres[ks*64+j][c].
    float w[64];
    {
        const float* wp = Wres + (size_t)(ks * 64) * RES + c;
        #pragma unroll
        for (int j = 0; j < 64; ++j) w[j] = wp[(size_t)j * RES];
    }

    // Staged state: row k (8 floats, 32 B) at byte addr k*32 + (k>>6)*16.
    // Pad per 64-row group -> the 4 ks-groups of a wave hit distinct banks.
    __shared__ __align__(16) float sst[8256];   // 33 KB
    __shared__ float pl[16][8][17];             // k-partial reduce, 8.7 KB

    u64cp* tgb = tg + (size_t)bg * 2 * RES * 8;

    const int fb = tid >> 4;               // finalize batch lane (tid < 128)
    float s_prev = 0.f;                    // register-carried state (b0+fb, c)

    for (int t = 0; t < T_STEPS; ++t) {
        u64cp* tgr = tgb + ((t & 1) ^ 1) * (RES * 8);  // published at t-1
        u64cp* tgw = tgb + (t & 1) * (RES * 8);        // being published at t

        // ---- Phase A: input projection (state-independent; overlaps poll)
        float x = 0.f;
        if (tid < 128) {
            const float* inb = inp + ((size_t)(b0 + fb) * T_STEPS + t) * IN_DIM;
            #pragma unroll
            for (int i = 0; i < IN_DIM; i += 4) {
                const float4 v = *reinterpret_cast<const float4*>(inb + i);
                x = fmaf(v.x, Win[(size_t)(i + 0) * RES + c], x);
                x = fmaf(v.y, Win[(size_t)(i + 1) * RES + c], x);
                x = fmaf(v.z, Win[(size_t)(i + 2) * RES + c], x);
                x = fmaf(v.w, Win[(size_t)(i + 3) * RES + c], x);
            }
        }

        // ---- Phase B: poll tagged words of step t-1, scatter into LDS.
        // Thread owns u64 indices {j*256 + tid : j=0..31} (8192 total).
        // Word idx -> row k = idx>>3, batch b = idx&7; LDS addr is linear in
        // tid per j (pad constant within a wave) -> conflict-free writes.
        if (t > 0) {
            const unsigned expt = (unsigned)(t - 1);
            const u64cp* tp = tgr + tid;
            unsigned pend = 0xFFFFFFFFu;
            while (pend) {
                #pragma unroll
                for (int j = 0; j < 32; ++j) {
                    if (pend & (1u << j)) {
                        const u64cp v = __hip_atomic_load(tp + j * 256,
                                            __ATOMIC_RELAXED, __HIP_MEMORY_SCOPE_AGENT);
                        if ((unsigned)(v >> 32) == expt) {
                            const int idx = j * 256 + tid;
                            const int k   = idx >> 3;
                            const int b   = idx & 7;
                            *(float*)((char*)sst + (size_t)k * 32 + ((k >> 6) * 16) + b * 4)
                                = __uint_as_float((unsigned)v);
                            pend &= ~(1u << j);
                        }
                    }
                }
            }
        }
        __syncthreads();

        // ---- Phase C: acc(b) = sum over k-chunk of W[k][c] * s[k][b], from LDS.
        float acc0 = 0.f, acc1 = 0.f, acc2 = 0.f, acc3 = 0.f;
        float acc4 = 0.f, acc5 = 0.f, acc6 = 0.f, acc7 = 0.f;
        if (t > 0) {
            const char* base = (const char*)sst + (size_t)(ks * 64) * 32 + ks * 16;
            #pragma unroll
            for (int j = 0; j < 64; ++j) {
                const float4 sa = *reinterpret_cast<const float4*>(base + j * 32);
                const float4 sb = *reinterpret_cast<const float4*>(base + j * 32 + 16);
                const float wj = w[j];
                acc0 = fmaf(sa.x, wj, acc0);
                acc1 = fmaf(sa.y, wj, acc1);
                acc2 = fmaf(sa.z, wj, acc2);
                acc3 = fmaf(sa.w, wj, acc3);
                acc4 = fmaf(sb.x, wj, acc4);
                acc5 = fmaf(sb.y, wj, acc5);
                acc6 = fmaf(sb.z, wj, acc6);
                acc7 = fmaf(sb.w, wj, acc7);
            }
        }

        // ---- Phase D: 16-way k-reduce through LDS, then finalize + publish.
        pl[ks][0][c_loc] = acc0;
        pl[ks][1][c_loc] = acc1;
        pl[ks][2][c_loc] = acc2;
        pl[ks][3][c_loc] = acc3;
        pl[ks][4][c_loc] = acc4;
        pl[ks][5][c_loc] = acc5;
        pl[ks][6][c_loc] = acc6;
        pl[ks][7][c_loc] = acc7;
        __syncthreads();

        if (tid < 128) {
            float sum = 0.f;
            #pragma unroll
            for (int q = 0; q < 16; ++q) sum += pl[q][fb][c_loc];

            const float nw = tanhf(x + sum);
            const float sn = fmaf(1.0f - LEAKF, s_prev, LEAKF * nw);
            s_prev = sn;

            out[((size_t)(b0 + fb) * T_STEPS + t) * RES + c] = sn;
            // Publish: value + tag in one 8-byte atomic store. Fire-and-forget.
            const u64cp word = ((u64cp)(unsigned)t << 32) | (u64cp)__float_as_uint(sn);
            __hip_atomic_store(tgw + (size_t)c * 8 + fb, word,
                               __ATOMIC_RELAXED, __HIP_MEMORY_SCOPE_AGENT);
        }
        // No trailing barrier needed: next step's LDS overwrites are gated by
        // the poll, which cannot succeed before our own writers (who finished
        // their pl/sst reads in program order) have published.
    }
}

// ---------------------------------------------------------------------------
// Fallback: proven per-step kernel (used only if ws too small).
// ---------------------------------------------------------------------------
__global__ __launch_bounds__(256) void esn_step(
    const float* __restrict__ inp,
    const float* __restrict__ Win,
    const float* __restrict__ Wres,
    float* __restrict__ out,
    float* __restrict__ sT,
    int t)
{
    const int tid   = threadIdx.x;
    const int c_loc = tid & 15;
    const int ks    = tid >> 4;
    const int c0    = blockIdx.x * 16;
    const int b0    = blockIdx.y * 8;
    const int c     = c0 + c_loc;

    const float* sTr = sT + ((t & 1) ^ 1) * (RES * NBATCH);
    float*       sTw = sT + (t & 1) * (RES * NBATCH);

    float acc0 = 0.f, acc1 = 0.f, acc2 = 0.f, acc3 = 0.f;
    float acc4 = 0.f, acc5 = 0.f, acc6 = 0.f, acc7 = 0.f;

    if (t > 0) {
        const int kbeg = ks * 64;
        const float* wp = Wres + (size_t)kbeg * RES + c;
        const float* sp = sTr + kbeg * NBATCH + b0;
        #pragma unroll 4
        for (int j = 0; j < 64; ++j) {
            const float w = wp[(size_t)j * RES];
            const float4 sa = *reinterpret_cast<const float4*>(sp + j * NBATCH);
            const float4 sb = *reinterpret_cast<const float4*>(sp + j * NBATCH + 4);
            acc0 = fmaf(sa.x, w, acc0);
            acc1 = fmaf(sa.y, w, acc1);
            acc2 = fmaf(sa.z, w, acc2);
            acc3 = fmaf(sa.w, w, acc3);
            acc4 = fmaf(sb.x, w, acc4);
            acc5 = fmaf(sb.y, w, acc5);
            acc6 = fmaf(sb.z, w, acc6);
            acc7 = fmaf(sb.w, w, acc7);
        }
    }

    __shared__ float pl[16][8][17];
    pl[ks][0][c_loc] = acc0;
    pl[ks][1][c_loc] = acc1;
    pl[ks][2][c_loc] = acc2;
    pl[ks][3][c_loc] = acc3;
    pl[ks][4][c_loc] = acc4;
    pl[ks][5][c_loc] = acc5;
    pl[ks][6][c_loc] = acc6;
    pl[ks][7][c_loc] = acc7;
    __syncthreads();

    if (tid < 128) {
        const int b  = tid >> 4;
        const int cl = tid & 15;
        const int cgl = c0 + cl;
        const int bgl = b0 + b;

        float sum = 0.f;
        #pragma unroll
        for (int q = 0; q < 16; ++q) sum += pl[q][b][cl];

        const float* inb = inp + ((size_t)bgl * T_STEPS + t) * IN_DIM;
        float x = 0.f;
        #pragma unroll 8
        for (int i = 0; i < IN_DIM; ++i)
            x = fmaf(inb[i], Win[(size_t)i * RES + cgl], x);

        const float a  = x + sum;
        const float nw = tanhf(a);
        const float spv = (t > 0) ? sTr[cgl * NBATCH + bgl] : 0.f;
        const float sn = fmaf(1.0f - LEAKF, spv, LEAKF * nw);

        out[((size_t)bgl * T_STEPS + t) * RES + cgl] = sn;
        sTw[cgl * NBATCH + bgl] = sn;
    }
}

extern "C" void kernel_launch(void* const* d_in, const int* in_sizes, int n_in,
                              void* d_out, int out_size, void* d_ws, size_t ws_size,
                              hipStream_t stream)
{
    const float* inp  = (const float*)d_in[0];   // [32,2048,64]
    const float* Win  = (const float*)d_in[1];   // [64,1024]
    const float* Wres = (const float*)d_in[2];   // [1024,1024]
    float* out = (float*)d_out;                  // [32,2048,1024]

    const size_t tagBytes = (size_t)NBG * 2 * RES * 8 * sizeof(u64cp);  // 512 KB

    if (ws_size >= tagBytes) {
        u64cp* tg = (u64cp*)d_ws;
        // Invalidate all tags (incl. stale 2046/2047 from a previous replay).
        hipMemsetAsync(tg, 0xFF, tagBytes, stream);
        hipLaunchKernelGGL(esn_persist, dim3(NCG, NBG), dim3(256), 0, stream,
                           inp, Win, Wres, out, tg);
        return;
    }

    // Workspace too small for tagged buffers: proven per-step path (256 KB).
    float* sT = (float*)d_ws;   // [2][1024][32]
    dim3 grid(64, 4), blk(256);
    for (int t = 0; t < T_STEPS; ++t) {
        hipLaunchKernelGGL(esn_step, grid, blk, 0, stream,
                           inp, Win, Wres, out, sT, t);
    }
}